// Round 1
// baseline (831.190 us; speedup 1.0000x reference)
//
#include <hip/hip_runtime.h>

#define N_NODES 10000
#define N_EDGES 320000
#define NODE_DIM 128
#define EDGE_DIM 16
#define HIDDEN 256
#define N_OUT 8
#define N_GRAPHS 64

// ---------------- CSR build ----------------
__global__ void hist_kernel(const int* __restrict__ dst, int* __restrict__ counts, int E) {
  int e = blockIdx.x * blockDim.x + threadIdx.x;
  if (e < E) atomicAdd(&counts[dst[e]], 1);
}

__global__ void scan_kernel(const int* __restrict__ counts, int* __restrict__ offs,
                            int* __restrict__ cursor, int n) {
  __shared__ int part[256];
  int t = threadIdx.x;
  const int chunk = (n + 255) / 256;
  int base = t * chunk;
  int s = 0;
  for (int j = 0; j < chunk; ++j) { int i = base + j; if (i < n) s += counts[i]; }
  part[t] = s;
  __syncthreads();
  for (int off = 1; off < 256; off <<= 1) {
    int v = (t >= off) ? part[t - off] : 0;
    __syncthreads();
    part[t] += v;
    __syncthreads();
  }
  int run = (t == 0) ? 0 : part[t - 1];
  for (int j = 0; j < chunk; ++j) {
    int i = base + j;
    if (i < n) { offs[i] = run; cursor[i] = run; run += counts[i]; }
  }
  if (t == 255) offs[n] = run;
}

__global__ void scatter_kernel(const int* __restrict__ ei, const float* __restrict__ eattr,
                               int* __restrict__ cursor, int* __restrict__ csr_src,
                               float* __restrict__ csr_attr, int E) {
  int e = blockIdx.x * blockDim.x + threadIdx.x;
  if (e >= E) return;
  int s = ei[e];
  int d = ei[E + e];
  int slot = atomicAdd(&cursor[d], 1);
  csr_src[slot] = s;
  const float4* in = (const float4*)(eattr + (size_t)e * 16);
  float4* out = (float4*)(csr_attr + (size_t)slot * 16);
  out[0] = in[0]; out[1] = in[1]; out[2] = in[2]; out[3] = in[3];
}

// ---------------- node GEMM: C[N][512] = A[N][K] @ [Wl | Wr] + [bl | br] ----------------
__global__ __launch_bounds__(256) void gemm_node(
    const float* __restrict__ A, int M, int K,
    const float* __restrict__ Wl, const float* __restrict__ Wr,
    const float* __restrict__ bl, const float* __restrict__ br,
    float* __restrict__ C) {
  __shared__ float As[16][64];  // transposed A tile
  __shared__ float Bs[16][64];
  const int bm = blockIdx.x * 64;
  const int bn = blockIdx.y * 64;
  const float* W; const float* bias; int wc;
  if (bn < HIDDEN) { W = Wl; bias = bl; wc = bn; }
  else             { W = Wr; bias = br; wc = bn - HIDDEN; }
  const int t = threadIdx.x;
  const int ar = t >> 2, ac = (t & 3) << 2;
  const int kb = t >> 4, bc = (t & 15) << 2;
  const int tm = (t >> 4) << 2, tn = (t & 15) << 2;
  float c[4][4] = {};
  for (int k0 = 0; k0 < K; k0 += 16) {
    int arow = bm + ar; if (arow >= M) arow = M - 1;
    float4 av = *(const float4*)(A + (size_t)arow * K + k0 + ac);
    As[ac + 0][ar] = av.x; As[ac + 1][ar] = av.y;
    As[ac + 2][ar] = av.z; As[ac + 3][ar] = av.w;
    *(float4*)&Bs[kb][bc] = *(const float4*)(W + (size_t)(k0 + kb) * HIDDEN + wc + bc);
    __syncthreads();
#pragma unroll
    for (int kk = 0; kk < 16; ++kk) {
      float4 a4 = *(const float4*)&As[kk][tm];
      float4 b4 = *(const float4*)&Bs[kk][tn];
      float a[4] = {a4.x, a4.y, a4.z, a4.w};
      float b[4] = {b4.x, b4.y, b4.z, b4.w};
#pragma unroll
      for (int i = 0; i < 4; ++i)
#pragma unroll
        for (int j = 0; j < 4; ++j)
          c[i][j] = fmaf(a[i], b[j], c[i][j]);
    }
    __syncthreads();
  }
#pragma unroll
  for (int i = 0; i < 4; ++i) {
    int row = bm + tm + i;
    if (row < M) {
      float4 o;
      o.x = c[i][0] + bias[wc + tn + 0];
      o.y = c[i][1] + bias[wc + tn + 1];
      o.z = c[i][2] + bias[wc + tn + 2];
      o.w = c[i][3] + bias[wc + tn + 3];
      *(float4*)(C + (size_t)row * 512 + bn + tn) = o;
    }
  }
}

// ---------------- fused edge scoring + segment softmax + aggregate + BN + act ----------------
__global__ __launch_bounds__(256) void edge_gat(
    const float* __restrict__ xlr,
    const int* __restrict__ offs, const int* __restrict__ csr_src,
    const float* __restrict__ csr_attr,
    const float* __restrict__ We, const float* __restrict__ att,
    const float* __restrict__ bconv,
    const float* __restrict__ gamma, const float* __restrict__ beta,
    const float* __restrict__ mean, const float* __restrict__ var,
    float* __restrict__ hout, int relu_last) {
  const int i = blockIdx.x;
  const int t = threadIdx.x;
  const int w = t >> 6;
  const int l = t & 63;
  const int h4 = l << 2;

  float4 Wreg[16];
#pragma unroll
  for (int d = 0; d < 16; ++d)
    Wreg[d] = *(const float4*)(We + d * HIDDEN + h4);
  const float4 att4 = *(const float4*)(att + h4);
  const float4 xr4 = *(const float4*)(xlr + (size_t)i * 512 + HIDDEN + h4);

  const int rs = offs[i], re = offs[i + 1];
  float mrun = -1e30f, den = 0.f;
  float4 acc = make_float4(0.f, 0.f, 0.f, 0.f);

  for (int e = rs + w; e < re; e += 4) {
    const int s = csr_src[e];
    const float4 xl4 = *(const float4*)(xlr + (size_t)s * 512 + h4);
    const float4* ap = (const float4*)(csr_attr + (size_t)e * 16);
    float4 A0 = ap[0], A1 = ap[1], A2 = ap[2], A3 = ap[3];
    float a[16] = {A0.x, A0.y, A0.z, A0.w, A1.x, A1.y, A1.z, A1.w,
                   A2.x, A2.y, A2.z, A2.w, A3.x, A3.y, A3.z, A3.w};
    float4 ev = make_float4(0.f, 0.f, 0.f, 0.f);
#pragma unroll
    for (int d = 0; d < 16; ++d) {
      ev.x = fmaf(a[d], Wreg[d].x, ev.x);
      ev.y = fmaf(a[d], Wreg[d].y, ev.y);
      ev.z = fmaf(a[d], Wreg[d].z, ev.z);
      ev.w = fmaf(a[d], Wreg[d].w, ev.w);
    }
    float zx = xl4.x + xr4.x + ev.x; zx = fmaxf(zx, 0.2f * zx);
    float zy = xl4.y + xr4.y + ev.y; zy = fmaxf(zy, 0.2f * zy);
    float zz = xl4.z + xr4.z + ev.z; zz = fmaxf(zz, 0.2f * zz);
    float zw = xl4.w + xr4.w + ev.w; zw = fmaxf(zw, 0.2f * zw);
    float p = att4.x * zx;
    p = fmaf(att4.y, zy, p);
    p = fmaf(att4.z, zz, p);
    p = fmaf(att4.w, zw, p);
#pragma unroll
    for (int off = 32; off > 0; off >>= 1) p += __shfl_xor(p, off, 64);
    float nm = fmaxf(mrun, p);
    float sc = __expf(mrun - nm);
    float wg = __expf(p - nm);
    den = den * sc + wg;
    acc.x = fmaf(wg, xl4.x, acc.x * sc);
    acc.y = fmaf(wg, xl4.y, acc.y * sc);
    acc.z = fmaf(wg, xl4.z, acc.z * sc);
    acc.w = fmaf(wg, xl4.w, acc.w * sc);
    mrun = nm;
  }

  __shared__ float wacc[4][HIDDEN];
  __shared__ float wm[4], wden[4];
  if (l == 0) { wm[w] = mrun; wden[w] = den; }
  *(float4*)&wacc[w][h4] = acc;
  __syncthreads();

  float M2 = fmaxf(fmaxf(wm[0], wm[1]), fmaxf(wm[2], wm[3]));
  float num = 0.f, D = 0.f;
#pragma unroll
  for (int ww = 0; ww < 4; ++ww) {
    float f = __expf(wm[ww] - M2);
    num = fmaf(f, wacc[ww][t], num);
    D = fmaf(f, wden[ww], D);
  }
  float o = (D > 0.f) ? num / D : 0.f;
  o += bconv[t];
  o = (o - mean[t]) * rsqrtf(var[t] + 1e-5f) * gamma[t] + beta[t];
  o = relu_last ? fmaxf(o, 0.f) : fmaxf(o, 0.01f * o);
  hout[(size_t)i * HIDDEN + t] = o;
}

// ---------------- pooling + heads ----------------
__device__ __forceinline__ int lbound(const int* a, int n, int v) {
  int lo = 0, hi = n;
  while (lo < hi) { int m = (lo + hi) >> 1; if (a[m] < v) lo = m + 1; else hi = m; }
  return lo;
}

__global__ void pool_kernel(const float* __restrict__ h, const int* __restrict__ batch,
                            float* __restrict__ g) {
  const int gi = blockIdx.x;
  const int t = threadIdx.x;
  int s = lbound(batch, N_NODES, gi);
  int e = lbound(batch, N_NODES, gi + 1);
  float sum = 0.f;
  for (int i = s; i < e; ++i) sum += h[(size_t)i * HIDDEN + t];
  float c = (float)(e - s);
  g[gi * HIDDEN + t] = sum / fmaxf(c, 1.f);
}

__global__ void head_kernel(const float* __restrict__ g,
                            const float* __restrict__ w1, const float* __restrict__ b1,
                            const float* __restrict__ w2, const float* __restrict__ b2,
                            float* __restrict__ out) {
  int idx = blockIdx.x * 256 + threadIdx.x;
  if (idx >= N_GRAPHS * N_OUT * 2) return;
  int which = idx >> 9;
  int rem = idx & 511;
  int row = rem >> 3, col = rem & 7;
  const float* w = which ? w2 : w1;
  float s = which ? b2[col] : b1[col];
  for (int k = 0; k < HIDDEN; ++k) s = fmaf(g[row * HIDDEN + k], w[k * N_OUT + col], s);
  out[idx] = s;
}

extern "C" void kernel_launch(void* const* d_in, const int* in_sizes, int n_in,
                              void* d_out, int out_size, void* d_ws, size_t ws_size,
                              hipStream_t stream) {
  const float* x     = (const float*)d_in[0];
  const int*   ei    = (const int*)d_in[1];
  const float* eattr = (const float*)d_in[2];
  const int*   batch = (const int*)d_in[3];
  const float* Wl1   = (const float*)d_in[4];
  const float* Wr1   = (const float*)d_in[5];
  const float* We1   = (const float*)d_in[6];
  const float* bl1   = (const float*)d_in[7];
  const float* br1   = (const float*)d_in[8];
  const float* att1  = (const float*)d_in[9];
  const float* b1    = (const float*)d_in[10];
  const float* Wls   = (const float*)d_in[11];
  const float* Wrs   = (const float*)d_in[12];
  const float* Wes   = (const float*)d_in[13];
  const float* bls   = (const float*)d_in[14];
  const float* brs   = (const float*)d_in[15];
  const float* atts  = (const float*)d_in[16];
  const float* bs    = (const float*)d_in[17];
  const float* bng   = (const float*)d_in[18];
  const float* bnb   = (const float*)d_in[19];
  const float* bnm   = (const float*)d_in[20];
  const float* bnv   = (const float*)d_in[21];
  const float* l1w   = (const float*)d_in[22];
  const float* l1b   = (const float*)d_in[23];
  const float* l2w   = (const float*)d_in[24];
  const float* l2b   = (const float*)d_in[25];
  float* out = (float*)d_out;

  char* ws = (char*)d_ws;
  auto alloc = [&](size_t bytes) {
    char* p = ws;
    ws += (bytes + 255) & ~(size_t)255;
    return p;
  };
  int*   counts   = (int*)alloc((size_t)N_NODES * 4);
  int*   offs     = (int*)alloc((size_t)(N_NODES + 1) * 4);
  int*   cursor   = (int*)alloc((size_t)N_NODES * 4);
  int*   csr_src  = (int*)alloc((size_t)N_EDGES * 4);
  float* csr_attr = (float*)alloc((size_t)N_EDGES * 16 * 4);
  float* xlr      = (float*)alloc((size_t)N_NODES * 512 * 4);
  float* hA       = (float*)alloc((size_t)N_NODES * 256 * 4);
  float* hB       = (float*)alloc((size_t)N_NODES * 256 * 4);
  float* g        = (float*)alloc((size_t)N_GRAPHS * 256 * 4);

  hipMemsetAsync(counts, 0, (size_t)N_NODES * 4, stream);
  hist_kernel<<<(N_EDGES + 255) / 256, 256, 0, stream>>>(ei + N_EDGES, counts, N_EDGES);
  scan_kernel<<<1, 256, 0, stream>>>(counts, offs, cursor, N_NODES);
  scatter_kernel<<<(N_EDGES + 255) / 256, 256, 0, stream>>>(ei, eattr, cursor, csr_src,
                                                            csr_attr, N_EDGES);

  dim3 gemm_grid((N_NODES + 63) / 64, 8);
  const float* hin = x;
  for (int layer = 0; layer < 5; ++layer) {
    int K = (layer == 0) ? NODE_DIM : HIDDEN;
    const float* Wl = (layer == 0) ? Wl1 : Wls + (size_t)(layer - 1) * HIDDEN * HIDDEN;
    const float* Wr = (layer == 0) ? Wr1 : Wrs + (size_t)(layer - 1) * HIDDEN * HIDDEN;
    const float* We = (layer == 0) ? We1 : Wes + (size_t)(layer - 1) * EDGE_DIM * HIDDEN;
    const float* bl = (layer == 0) ? bl1 : bls + (layer - 1) * HIDDEN;
    const float* br = (layer == 0) ? br1 : brs + (layer - 1) * HIDDEN;
    const float* at = (layer == 0) ? att1 : atts + (layer - 1) * HIDDEN;
    const float* bc = (layer == 0) ? b1 : bs + (layer - 1) * HIDDEN;
    float* hout = (layer & 1) ? hB : hA;
    gemm_node<<<gemm_grid, 256, 0, stream>>>(hin, N_NODES, K, Wl, Wr, bl, br, xlr);
    edge_gat<<<N_NODES, 256, 0, stream>>>(xlr, offs, csr_src, csr_attr, We, at, bc,
                                          bng + layer * HIDDEN, bnb + layer * HIDDEN,
                                          bnm + layer * HIDDEN, bnv + layer * HIDDEN,
                                          hout, (layer == 4) ? 1 : 0);
    hin = hout;
  }
  pool_kernel<<<N_GRAPHS, 256, 0, stream>>>(hin, batch, g);
  head_kernel<<<4, 256, 0, stream>>>(g, l1w, l1b, l2w, l2b, out);
}

// Round 2
// 722.417 us; speedup vs baseline: 1.1506x; 1.1506x over previous
//
#include <hip/hip_runtime.h>

#define N_NODES 10000
#define N_EDGES 320000
#define NODE_DIM 128
#define EDGE_DIM 16
#define HIDDEN 256
#define N_OUT 8
#define N_GRAPHS 64

// ---------------- CSR build ----------------
__global__ void hist_kernel(const int* __restrict__ dst, int* __restrict__ counts, int E) {
  int e = blockIdx.x * blockDim.x + threadIdx.x;
  if (e < E) atomicAdd(&counts[dst[e]], 1);
}

__global__ void scan_kernel(const int* __restrict__ counts, int* __restrict__ offs,
                            int* __restrict__ cursor, int n) {
  __shared__ int part[256];
  int t = threadIdx.x;
  const int chunk = (n + 255) / 256;
  int base = t * chunk;
  int s = 0;
  for (int j = 0; j < chunk; ++j) { int i = base + j; if (i < n) s += counts[i]; }
  part[t] = s;
  __syncthreads();
  for (int off = 1; off < 256; off <<= 1) {
    int v = (t >= off) ? part[t - off] : 0;
    __syncthreads();
    part[t] += v;
    __syncthreads();
  }
  int run = (t == 0) ? 0 : part[t - 1];
  for (int j = 0; j < chunk; ++j) {
    int i = base + j;
    if (i < n) { offs[i] = run; cursor[i] = run; run += counts[i]; }
  }
  if (t == 255) offs[n] = run;
}

__global__ void scatter_kernel(const int* __restrict__ ei, const float* __restrict__ eattr,
                               int* __restrict__ cursor, int* __restrict__ csr_src,
                               float* __restrict__ csr_attr, int E) {
  int e = blockIdx.x * blockDim.x + threadIdx.x;
  if (e >= E) return;
  int s = ei[e];
  int d = ei[E + e];
  int slot = atomicAdd(&cursor[d], 1);
  csr_src[slot] = s;
  const float4* in = (const float4*)(eattr + (size_t)e * 16);
  float4* out = (float4*)(csr_attr + (size_t)slot * 16);
  out[0] = in[0]; out[1] = in[1]; out[2] = in[2]; out[3] = in[3];
}

// ---------------- node GEMM: C[N][512] = A[N][K] @ [Wl | Wr] + [bl | br] ----------------
__global__ __launch_bounds__(256) void gemm_node(
    const float* __restrict__ A, int M, int K,
    const float* __restrict__ Wl, const float* __restrict__ Wr,
    const float* __restrict__ bl, const float* __restrict__ br,
    float* __restrict__ C) {
  __shared__ float As[16][64];  // transposed A tile
  __shared__ float Bs[16][64];
  const int bm = blockIdx.x * 64;
  const int bn = blockIdx.y * 64;
  const float* W; const float* bias; int wc;
  if (bn < HIDDEN) { W = Wl; bias = bl; wc = bn; }
  else             { W = Wr; bias = br; wc = bn - HIDDEN; }
  const int t = threadIdx.x;
  const int ar = t >> 2, ac = (t & 3) << 2;
  const int kb = t >> 4, bc = (t & 15) << 2;
  const int tm = (t >> 4) << 2, tn = (t & 15) << 2;
  float c[4][4] = {};
  for (int k0 = 0; k0 < K; k0 += 16) {
    int arow = bm + ar; if (arow >= M) arow = M - 1;
    float4 av = *(const float4*)(A + (size_t)arow * K + k0 + ac);
    As[ac + 0][ar] = av.x; As[ac + 1][ar] = av.y;
    As[ac + 2][ar] = av.z; As[ac + 3][ar] = av.w;
    *(float4*)&Bs[kb][bc] = *(const float4*)(W + (size_t)(k0 + kb) * HIDDEN + wc + bc);
    __syncthreads();
#pragma unroll
    for (int kk = 0; kk < 16; ++kk) {
      float4 a4 = *(const float4*)&As[kk][tm];
      float4 b4 = *(const float4*)&Bs[kk][tn];
      float a[4] = {a4.x, a4.y, a4.z, a4.w};
      float b[4] = {b4.x, b4.y, b4.z, b4.w};
#pragma unroll
      for (int i = 0; i < 4; ++i)
#pragma unroll
        for (int j = 0; j < 4; ++j)
          c[i][j] = fmaf(a[i], b[j], c[i][j]);
    }
    __syncthreads();
  }
#pragma unroll
  for (int i = 0; i < 4; ++i) {
    int row = bm + tm + i;
    if (row < M) {
      float4 o;
      o.x = c[i][0] + bias[wc + tn + 0];
      o.y = c[i][1] + bias[wc + tn + 1];
      o.z = c[i][2] + bias[wc + tn + 2];
      o.w = c[i][3] + bias[wc + tn + 3];
      *(float4*)(C + (size_t)row * 512 + bn + tn) = o;
    }
  }
}

// ---------------- fused edge scoring + segment softmax + aggregate + BN + act ----------------
// One wave per destination node. All per-edge scalars forced wave-uniform via
// readfirstlane so edge attr loads become s_load and the xl gather gets an SGPR
// base. 1-deep prefetch of next edge. launch_bounds(256,4): 128 VGPR cap keeps
// Wreg[16] (64 VGPRs) resident.
__global__ __launch_bounds__(256, 4) void edge_gat(
    const float* __restrict__ xlr,
    const int* __restrict__ offs, const int* __restrict__ csr_src,
    const float* __restrict__ csr_attr,
    const float* __restrict__ We, const float* __restrict__ att,
    const float* __restrict__ bconv,
    const float* __restrict__ gamma, const float* __restrict__ beta,
    const float* __restrict__ mean, const float* __restrict__ var,
    float* __restrict__ hout, int relu_last) {
  const int t = threadIdx.x;
  const int w = t >> 6;
  const int l = t & 63;
  const int h4 = l << 2;
  const int iu = __builtin_amdgcn_readfirstlane(blockIdx.x * 4 + w);

  float4 Wreg[16];
#pragma unroll
  for (int d = 0; d < 16; ++d)
    Wreg[d] = *(const float4*)(We + d * HIDDEN + h4);
  const float4 att4 = *(const float4*)(att + h4);
  const float4 xr4 = *(const float4*)(xlr + (size_t)iu * 512 + HIDDEN + h4);

  const int rs = __builtin_amdgcn_readfirstlane(offs[iu]);
  const int re = __builtin_amdgcn_readfirstlane(offs[iu + 1]);

  float mrun = -1e30f, den = 0.f;
  float4 acc = make_float4(0.f, 0.f, 0.f, 0.f);

  int e = rs;
  float4 xln = make_float4(0.f, 0.f, 0.f, 0.f);
  float an[16];
#pragma unroll
  for (int d = 0; d < 16; ++d) an[d] = 0.f;
  if (e < re) {
    int sn = __builtin_amdgcn_readfirstlane(csr_src[e]);
    xln = *(const float4*)(xlr + (size_t)sn * 512 + h4);
    const float* ap = csr_attr + (size_t)e * 16;
#pragma unroll
    for (int d = 0; d < 16; ++d) an[d] = ap[d];
  }

  for (; e < re; ++e) {
    const float4 xl4 = xln;
    float a[16];
#pragma unroll
    for (int d = 0; d < 16; ++d) a[d] = an[d];
    const int en = e + 1;
    if (en < re) {
      int sn = __builtin_amdgcn_readfirstlane(csr_src[en]);
      xln = *(const float4*)(xlr + (size_t)sn * 512 + h4);
      const float* ap = csr_attr + (size_t)en * 16;
#pragma unroll
      for (int d = 0; d < 16; ++d) an[d] = ap[d];
    }

    float4 ev = make_float4(0.f, 0.f, 0.f, 0.f);
#pragma unroll
    for (int d = 0; d < 16; ++d) {
      ev.x = fmaf(a[d], Wreg[d].x, ev.x);
      ev.y = fmaf(a[d], Wreg[d].y, ev.y);
      ev.z = fmaf(a[d], Wreg[d].z, ev.z);
      ev.w = fmaf(a[d], Wreg[d].w, ev.w);
    }
    float zx = xl4.x + xr4.x + ev.x; zx = fmaxf(zx, 0.2f * zx);
    float zy = xl4.y + xr4.y + ev.y; zy = fmaxf(zy, 0.2f * zy);
    float zz = xl4.z + xr4.z + ev.z; zz = fmaxf(zz, 0.2f * zz);
    float zw = xl4.w + xr4.w + ev.w; zw = fmaxf(zw, 0.2f * zw);
    float p = att4.x * zx;
    p = fmaf(att4.y, zy, p);
    p = fmaf(att4.z, zz, p);
    p = fmaf(att4.w, zw, p);
#pragma unroll
    for (int off = 32; off > 0; off >>= 1) p += __shfl_xor(p, off, 64);
    const float nm = fmaxf(mrun, p);
    const float sc = __expf(mrun - nm);
    const float wg = __expf(p - nm);
    den = den * sc + wg;
    acc.x = fmaf(wg, xl4.x, acc.x * sc);
    acc.y = fmaf(wg, xl4.y, acc.y * sc);
    acc.z = fmaf(wg, xl4.z, acc.z * sc);
    acc.w = fmaf(wg, xl4.w, acc.w * sc);
    mrun = nm;
  }

  const float inv = (den > 0.f) ? __frcp_rn(den) : 0.f;
  const float4 bc4 = *(const float4*)(bconv + h4);
  const float4 g4 = *(const float4*)(gamma + h4);
  const float4 b4 = *(const float4*)(beta + h4);
  const float4 m4 = *(const float4*)(mean + h4);
  const float4 v4 = *(const float4*)(var + h4);
  float o[4];
  o[0] = fmaf(acc.x, inv, bc4.x);
  o[1] = fmaf(acc.y, inv, bc4.y);
  o[2] = fmaf(acc.z, inv, bc4.z);
  o[3] = fmaf(acc.w, inv, bc4.w);
  const float gm[4] = {g4.x, g4.y, g4.z, g4.w};
  const float bt[4] = {b4.x, b4.y, b4.z, b4.w};
  const float mn[4] = {m4.x, m4.y, m4.z, m4.w};
  const float vr[4] = {v4.x, v4.y, v4.z, v4.w};
  float4 res;
  float* rp = (float*)&res;
#pragma unroll
  for (int j = 0; j < 4; ++j) {
    float y = (o[j] - mn[j]) * rsqrtf(vr[j] + 1e-5f) * gm[j] + bt[j];
    rp[j] = relu_last ? fmaxf(y, 0.f) : fmaxf(y, 0.01f * y);
  }
  *(float4*)(hout + (size_t)iu * HIDDEN + h4) = res;
}

// ---------------- pooling + heads ----------------
__device__ __forceinline__ int lbound(const int* a, int n, int v) {
  int lo = 0, hi = n;
  while (lo < hi) { int m = (lo + hi) >> 1; if (a[m] < v) lo = m + 1; else hi = m; }
  return lo;
}

__global__ void pool_kernel(const float* __restrict__ h, const int* __restrict__ batch,
                            float* __restrict__ g) {
  const int gi = blockIdx.x;
  const int t = threadIdx.x;
  int s = lbound(batch, N_NODES, gi);
  int e = lbound(batch, N_NODES, gi + 1);
  float sum = 0.f;
  for (int i = s; i < e; ++i) sum += h[(size_t)i * HIDDEN + t];
  float c = (float)(e - s);
  g[gi * HIDDEN + t] = sum / fmaxf(c, 1.f);
}

__global__ void head_kernel(const float* __restrict__ g,
                            const float* __restrict__ w1, const float* __restrict__ b1,
                            const float* __restrict__ w2, const float* __restrict__ b2,
                            float* __restrict__ out) {
  int idx = blockIdx.x * 256 + threadIdx.x;
  if (idx >= N_GRAPHS * N_OUT * 2) return;
  int which = idx >> 9;
  int rem = idx & 511;
  int row = rem >> 3, col = rem & 7;
  const float* w = which ? w2 : w1;
  float s = which ? b2[col] : b1[col];
  for (int k = 0; k < HIDDEN; ++k) s = fmaf(g[row * HIDDEN + k], w[k * N_OUT + col], s);
  out[idx] = s;
}

extern "C" void kernel_launch(void* const* d_in, const int* in_sizes, int n_in,
                              void* d_out, int out_size, void* d_ws, size_t ws_size,
                              hipStream_t stream) {
  const float* x     = (const float*)d_in[0];
  const int*   ei    = (const int*)d_in[1];
  const float* eattr = (const float*)d_in[2];
  const int*   batch = (const int*)d_in[3];
  const float* Wl1   = (const float*)d_in[4];
  const float* Wr1   = (const float*)d_in[5];
  const float* We1   = (const float*)d_in[6];
  const float* bl1   = (const float*)d_in[7];
  const float* br1   = (const float*)d_in[8];
  const float* att1  = (const float*)d_in[9];
  const float* b1    = (const float*)d_in[10];
  const float* Wls   = (const float*)d_in[11];
  const float* Wrs   = (const float*)d_in[12];
  const float* Wes   = (const float*)d_in[13];
  const float* bls   = (const float*)d_in[14];
  const float* brs   = (const float*)d_in[15];
  const float* atts  = (const float*)d_in[16];
  const float* bs    = (const float*)d_in[17];
  const float* bng   = (const float*)d_in[18];
  const float* bnb   = (const float*)d_in[19];
  const float* bnm   = (const float*)d_in[20];
  const float* bnv   = (const float*)d_in[21];
  const float* l1w   = (const float*)d_in[22];
  const float* l1b   = (const float*)d_in[23];
  const float* l2w   = (const float*)d_in[24];
  const float* l2b   = (const float*)d_in[25];
  float* out = (float*)d_out;

  char* ws = (char*)d_ws;
  auto alloc = [&](size_t bytes) {
    char* p = ws;
    ws += (bytes + 255) & ~(size_t)255;
    return p;
  };
  int*   counts   = (int*)alloc((size_t)N_NODES * 4);
  int*   offs     = (int*)alloc((size_t)(N_NODES + 1) * 4);
  int*   cursor   = (int*)alloc((size_t)N_NODES * 4);
  int*   csr_src  = (int*)alloc((size_t)N_EDGES * 4);
  float* csr_attr = (float*)alloc((size_t)N_EDGES * 16 * 4);
  float* xlr      = (float*)alloc((size_t)N_NODES * 512 * 4);
  float* hA       = (float*)alloc((size_t)N_NODES * 256 * 4);
  float* hB       = (float*)alloc((size_t)N_NODES * 256 * 4);
  float* g        = (float*)alloc((size_t)N_GRAPHS * 256 * 4);

  hipMemsetAsync(counts, 0, (size_t)N_NODES * 4, stream);
  hist_kernel<<<(N_EDGES + 255) / 256, 256, 0, stream>>>(ei + N_EDGES, counts, N_EDGES);
  scan_kernel<<<1, 256, 0, stream>>>(counts, offs, cursor, N_NODES);
  scatter_kernel<<<(N_EDGES + 255) / 256, 256, 0, stream>>>(ei, eattr, cursor, csr_src,
                                                            csr_attr, N_EDGES);

  dim3 gemm_grid((N_NODES + 63) / 64, 8);
  const float* hin = x;
  for (int layer = 0; layer < 5; ++layer) {
    int K = (layer == 0) ? NODE_DIM : HIDDEN;
    const float* Wl = (layer == 0) ? Wl1 : Wls + (size_t)(layer - 1) * HIDDEN * HIDDEN;
    const float* Wr = (layer == 0) ? Wr1 : Wrs + (size_t)(layer - 1) * HIDDEN * HIDDEN;
    const float* We = (layer == 0) ? We1 : Wes + (size_t)(layer - 1) * EDGE_DIM * HIDDEN;
    const float* bl = (layer == 0) ? bl1 : bls + (layer - 1) * HIDDEN;
    const float* br = (layer == 0) ? br1 : brs + (layer - 1) * HIDDEN;
    const float* at = (layer == 0) ? att1 : atts + (layer - 1) * HIDDEN;
    const float* bc = (layer == 0) ? b1 : bs + (layer - 1) * HIDDEN;
    float* hout = (layer & 1) ? hB : hA;
    gemm_node<<<gemm_grid, 256, 0, stream>>>(hin, N_NODES, K, Wl, Wr, bl, br, xlr);
    edge_gat<<<N_NODES / 4, 256, 0, stream>>>(xlr, offs, csr_src, csr_attr, We, at, bc,
                                              bng + layer * HIDDEN, bnb + layer * HIDDEN,
                                              bnm + layer * HIDDEN, bnv + layer * HIDDEN,
                                              hout, (layer == 4) ? 1 : 0);
    hin = hout;
  }
  pool_kernel<<<N_GRAPHS, 256, 0, stream>>>(hin, batch, g);
  head_kernel<<<4, 256, 0, stream>>>(g, l1w, l1b, l2w, l2b, out);
}

// Round 3
// 685.373 us; speedup vs baseline: 1.2128x; 1.0541x over previous
//
#include <hip/hip_runtime.h>

#define N_NODES 10000
#define N_EDGES 320000
#define NODE_DIM 128
#define EDGE_DIM 16
#define HIDDEN 256
#define N_OUT 8
#define N_GRAPHS 64
#define LOG2E 1.4426950408889634f

// ---------------- CSR build ----------------
__global__ void hist_kernel(const int* __restrict__ dst, int* __restrict__ counts, int E) {
  int e = blockIdx.x * blockDim.x + threadIdx.x;
  if (e < E) atomicAdd(&counts[dst[e]], 1);
}

__global__ void scan_kernel(const int* __restrict__ counts, int* __restrict__ offs,
                            int* __restrict__ cursor, int n) {
  __shared__ int part[256];
  int t = threadIdx.x;
  const int chunk = (n + 255) / 256;
  int base = t * chunk;
  int s = 0;
  for (int j = 0; j < chunk; ++j) { int i = base + j; if (i < n) s += counts[i]; }
  part[t] = s;
  __syncthreads();
  for (int off = 1; off < 256; off <<= 1) {
    int v = (t >= off) ? part[t - off] : 0;
    __syncthreads();
    part[t] += v;
    __syncthreads();
  }
  int run = (t == 0) ? 0 : part[t - 1];
  for (int j = 0; j < chunk; ++j) {
    int i = base + j;
    if (i < n) { offs[i] = run; cursor[i] = run; run += counts[i]; }
  }
  if (t == 255) offs[n] = run;
}

__global__ void scatter_kernel(const int* __restrict__ ei, const float* __restrict__ eattr,
                               int* __restrict__ cursor, int* __restrict__ csr_src,
                               float* __restrict__ csr_attr, int E) {
  int e = blockIdx.x * blockDim.x + threadIdx.x;
  if (e >= E) return;
  int s = ei[e];
  int d = ei[E + e];
  int slot = atomicAdd(&cursor[d], 1);
  csr_src[slot] = s;
  const float4* in = (const float4*)(eattr + (size_t)e * 16);
  float4* out = (float4*)(csr_attr + (size_t)slot * 16);
  out[0] = in[0]; out[1] = in[1]; out[2] = in[2]; out[3] = in[3];
}

// ---------------- node GEMM: C[N][512] = A[N][K] @ [Wl | Wr] + [bl | br] ----------------
__global__ __launch_bounds__(256) void gemm_node(
    const float* __restrict__ A, int M, int K,
    const float* __restrict__ Wl, const float* __restrict__ Wr,
    const float* __restrict__ bl, const float* __restrict__ br,
    float* __restrict__ C) {
  __shared__ float As[16][64];  // transposed A tile
  __shared__ float Bs[16][64];
  const int bm = blockIdx.x * 64;
  const int bn = blockIdx.y * 64;
  const float* W; const float* bias; int wc;
  if (bn < HIDDEN) { W = Wl; bias = bl; wc = bn; }
  else             { W = Wr; bias = br; wc = bn - HIDDEN; }
  const int t = threadIdx.x;
  const int ar = t >> 2, ac = (t & 3) << 2;
  const int kb = t >> 4, bc = (t & 15) << 2;
  const int tm = (t >> 4) << 2, tn = (t & 15) << 2;
  float c[4][4] = {};
  for (int k0 = 0; k0 < K; k0 += 16) {
    int arow = bm + ar; if (arow >= M) arow = M - 1;
    float4 av = *(const float4*)(A + (size_t)arow * K + k0 + ac);
    As[ac + 0][ar] = av.x; As[ac + 1][ar] = av.y;
    As[ac + 2][ar] = av.z; As[ac + 3][ar] = av.w;
    *(float4*)&Bs[kb][bc] = *(const float4*)(W + (size_t)(k0 + kb) * HIDDEN + wc + bc);
    __syncthreads();
#pragma unroll
    for (int kk = 0; kk < 16; ++kk) {
      float4 a4 = *(const float4*)&As[kk][tm];
      float4 b4 = *(const float4*)&Bs[kk][tn];
      float a[4] = {a4.x, a4.y, a4.z, a4.w};
      float b[4] = {b4.x, b4.y, b4.z, b4.w};
#pragma unroll
      for (int i = 0; i < 4; ++i)
#pragma unroll
        for (int j = 0; j < 4; ++j)
          c[i][j] = fmaf(a[i], b[j], c[i][j]);
    }
    __syncthreads();
  }
#pragma unroll
  for (int i = 0; i < 4; ++i) {
    int row = bm + tm + i;
    if (row < M) {
      float4 o;
      o.x = c[i][0] + bias[wc + tn + 0];
      o.y = c[i][1] + bias[wc + tn + 1];
      o.z = c[i][2] + bias[wc + tn + 2];
      o.w = c[i][3] + bias[wc + tn + 3];
      *(float4*)(C + (size_t)row * 512 + bn + tn) = o;
    }
  }
}

// ---------------- fused edge scoring + segment softmax + aggregate + BN + act ----------------
// One wave per destination node; 4 edges per iteration (batched online softmax:
// one rescale + 5 exp per 4 edges, 4 gathers in flight). Edge scalars wave-uniform
// (s_load). att pre-scaled by log2e -> exp2f (native v_exp_f32).
__global__ __launch_bounds__(256, 4) void edge_gat(
    const float* __restrict__ xlr,
    const int* __restrict__ offs, const int* __restrict__ csr_src,
    const float* __restrict__ csr_attr,
    const float* __restrict__ We, const float* __restrict__ att,
    const float* __restrict__ bconv,
    const float* __restrict__ gamma, const float* __restrict__ beta,
    const float* __restrict__ mean, const float* __restrict__ var,
    float* __restrict__ hout, int relu_last) {
  const int t = threadIdx.x;
  const int w = t >> 6;
  const int l = t & 63;
  const int h4 = l << 2;
  const int iu = __builtin_amdgcn_readfirstlane(blockIdx.x * 4 + w);

  float4 Wreg[16];
#pragma unroll
  for (int d = 0; d < 16; ++d)
    Wreg[d] = *(const float4*)(We + d * HIDDEN + h4);
  float4 att4 = *(const float4*)(att + h4);
  att4.x *= LOG2E; att4.y *= LOG2E; att4.z *= LOG2E; att4.w *= LOG2E;
  const float4 xr4 = *(const float4*)(xlr + (size_t)iu * 512 + HIDDEN + h4);

  const int rs = __builtin_amdgcn_readfirstlane(offs[iu]);
  const int re = __builtin_amdgcn_readfirstlane(offs[iu + 1]);

  float mrun = -1e30f, den = 0.f;
  float4 acc = make_float4(0.f, 0.f, 0.f, 0.f);

  for (int e = rs; e < re; e += 4) {
    const int e0 = e;
    const int e1 = (e + 1 < re) ? e + 1 : e;
    const int e2 = (e + 2 < re) ? e + 2 : e;
    const int e3 = (e + 3 < re) ? e + 3 : e;
    const int s0 = __builtin_amdgcn_readfirstlane(csr_src[e0]);
    const int s1 = __builtin_amdgcn_readfirstlane(csr_src[e1]);
    const int s2 = __builtin_amdgcn_readfirstlane(csr_src[e2]);
    const int s3 = __builtin_amdgcn_readfirstlane(csr_src[e3]);
    const float4 xl0 = *(const float4*)(xlr + (size_t)s0 * 512 + h4);
    const float4 xl1 = *(const float4*)(xlr + (size_t)s1 * 512 + h4);
    const float4 xl2 = *(const float4*)(xlr + (size_t)s2 * 512 + h4);
    const float4 xl3 = *(const float4*)(xlr + (size_t)s3 * 512 + h4);
    const float* a0 = csr_attr + (size_t)e0 * 16;
    const float* a1 = csr_attr + (size_t)e1 * 16;
    const float* a2 = csr_attr + (size_t)e2 * 16;
    const float* a3 = csr_attr + (size_t)e3 * 16;

    float4 z0 = xr4, z1 = xr4, z2 = xr4, z3 = xr4;
#pragma unroll
    for (int d = 0; d < 16; ++d) {
      const float4 wd = Wreg[d];
      z0.x = fmaf(a0[d], wd.x, z0.x); z0.y = fmaf(a0[d], wd.y, z0.y);
      z0.z = fmaf(a0[d], wd.z, z0.z); z0.w = fmaf(a0[d], wd.w, z0.w);
      z1.x = fmaf(a1[d], wd.x, z1.x); z1.y = fmaf(a1[d], wd.y, z1.y);
      z1.z = fmaf(a1[d], wd.z, z1.z); z1.w = fmaf(a1[d], wd.w, z1.w);
      z2.x = fmaf(a2[d], wd.x, z2.x); z2.y = fmaf(a2[d], wd.y, z2.y);
      z2.z = fmaf(a2[d], wd.z, z2.z); z2.w = fmaf(a2[d], wd.w, z2.w);
      z3.x = fmaf(a3[d], wd.x, z3.x); z3.y = fmaf(a3[d], wd.y, z3.y);
      z3.z = fmaf(a3[d], wd.z, z3.z); z3.w = fmaf(a3[d], wd.w, z3.w);
    }
    float p0, p1, p2, p3;
    {
      float zx, zy, zz, zw;
      zx = z0.x + xl0.x; zy = z0.y + xl0.y; zz = z0.z + xl0.z; zw = z0.w + xl0.w;
      zx = fmaxf(zx, 0.2f * zx); zy = fmaxf(zy, 0.2f * zy);
      zz = fmaxf(zz, 0.2f * zz); zw = fmaxf(zw, 0.2f * zw);
      p0 = att4.x * zx; p0 = fmaf(att4.y, zy, p0); p0 = fmaf(att4.z, zz, p0); p0 = fmaf(att4.w, zw, p0);
      zx = z1.x + xl1.x; zy = z1.y + xl1.y; zz = z1.z + xl1.z; zw = z1.w + xl1.w;
      zx = fmaxf(zx, 0.2f * zx); zy = fmaxf(zy, 0.2f * zy);
      zz = fmaxf(zz, 0.2f * zz); zw = fmaxf(zw, 0.2f * zw);
      p1 = att4.x * zx; p1 = fmaf(att4.y, zy, p1); p1 = fmaf(att4.z, zz, p1); p1 = fmaf(att4.w, zw, p1);
      zx = z2.x + xl2.x; zy = z2.y + xl2.y; zz = z2.z + xl2.z; zw = z2.w + xl2.w;
      zx = fmaxf(zx, 0.2f * zx); zy = fmaxf(zy, 0.2f * zy);
      zz = fmaxf(zz, 0.2f * zz); zw = fmaxf(zw, 0.2f * zw);
      p2 = att4.x * zx; p2 = fmaf(att4.y, zy, p2); p2 = fmaf(att4.z, zz, p2); p2 = fmaf(att4.w, zw, p2);
      zx = z3.x + xl3.x; zy = z3.y + xl3.y; zz = z3.z + xl3.z; zw = z3.w + xl3.w;
      zx = fmaxf(zx, 0.2f * zx); zy = fmaxf(zy, 0.2f * zy);
      zz = fmaxf(zz, 0.2f * zz); zw = fmaxf(zw, 0.2f * zw);
      p3 = att4.x * zx; p3 = fmaf(att4.y, zy, p3); p3 = fmaf(att4.z, zz, p3); p3 = fmaf(att4.w, zw, p3);
    }
#pragma unroll
    for (int off = 32; off > 0; off >>= 1) {
      p0 += __shfl_xor(p0, off, 64);
      p1 += __shfl_xor(p1, off, 64);
      p2 += __shfl_xor(p2, off, 64);
      p3 += __shfl_xor(p3, off, 64);
    }
    if (e + 1 >= re) p1 = -1e30f;
    if (e + 2 >= re) p2 = -1e30f;
    if (e + 3 >= re) p3 = -1e30f;

    const float bm = fmaxf(fmaxf(p0, p1), fmaxf(p2, p3));
    const float nm = fmaxf(mrun, bm);
    const float sc = exp2f(mrun - nm);
    const float w0 = exp2f(p0 - nm);
    const float w1 = exp2f(p1 - nm);
    const float w2 = exp2f(p2 - nm);
    const float w3 = exp2f(p3 - nm);
    den = fmaf(den, sc, (w0 + w1) + (w2 + w3));
    float tx = w0 * xl0.x; tx = fmaf(w1, xl1.x, tx); tx = fmaf(w2, xl2.x, tx); tx = fmaf(w3, xl3.x, tx);
    float ty = w0 * xl0.y; ty = fmaf(w1, xl1.y, ty); ty = fmaf(w2, xl2.y, ty); ty = fmaf(w3, xl3.y, ty);
    float tz = w0 * xl0.z; tz = fmaf(w1, xl1.z, tz); tz = fmaf(w2, xl2.z, tz); tz = fmaf(w3, xl3.z, tz);
    float tw = w0 * xl0.w; tw = fmaf(w1, xl1.w, tw); tw = fmaf(w2, xl2.w, tw); tw = fmaf(w3, xl3.w, tw);
    acc.x = fmaf(acc.x, sc, tx);
    acc.y = fmaf(acc.y, sc, ty);
    acc.z = fmaf(acc.z, sc, tz);
    acc.w = fmaf(acc.w, sc, tw);
    mrun = nm;
  }

  const float inv = (den > 0.f) ? __frcp_rn(den) : 0.f;
  const float4 bc4 = *(const float4*)(bconv + h4);
  const float4 g4 = *(const float4*)(gamma + h4);
  const float4 b4 = *(const float4*)(beta + h4);
  const float4 m4 = *(const float4*)(mean + h4);
  const float4 v4 = *(const float4*)(var + h4);
  float o[4];
  o[0] = fmaf(acc.x, inv, bc4.x);
  o[1] = fmaf(acc.y, inv, bc4.y);
  o[2] = fmaf(acc.z, inv, bc4.z);
  o[3] = fmaf(acc.w, inv, bc4.w);
  const float gm[4] = {g4.x, g4.y, g4.z, g4.w};
  const float bt[4] = {b4.x, b4.y, b4.z, b4.w};
  const float mn[4] = {m4.x, m4.y, m4.z, m4.w};
  const float vr[4] = {v4.x, v4.y, v4.z, v4.w};
  float4 res;
  float* rp = (float*)&res;
#pragma unroll
  for (int j = 0; j < 4; ++j) {
    float y = (o[j] - mn[j]) * rsqrtf(vr[j] + 1e-5f) * gm[j] + bt[j];
    rp[j] = relu_last ? fmaxf(y, 0.f) : fmaxf(y, 0.01f * y);
  }
  *(float4*)(hout + (size_t)iu * HIDDEN + h4) = res;
}

// ---------------- pooling + heads ----------------
__device__ __forceinline__ int lbound(const int* a, int n, int v) {
  int lo = 0, hi = n;
  while (lo < hi) { int m = (lo + hi) >> 1; if (a[m] < v) lo = m + 1; else hi = m; }
  return lo;
}

__global__ void pool_kernel(const float* __restrict__ h, const int* __restrict__ batch,
                            float* __restrict__ g) {
  const int gi = blockIdx.x;
  const int t = threadIdx.x;
  int s = lbound(batch, N_NODES, gi);
  int e = lbound(batch, N_NODES, gi + 1);
  float sum = 0.f;
  for (int i = s; i < e; ++i) sum += h[(size_t)i * HIDDEN + t];
  float c = (float)(e - s);
  g[gi * HIDDEN + t] = sum / fmaxf(c, 1.f);
}

__global__ void head_kernel(const float* __restrict__ g,
                            const float* __restrict__ w1, const float* __restrict__ b1,
                            const float* __restrict__ w2, const float* __restrict__ b2,
                            float* __restrict__ out) {
  int idx = blockIdx.x * 256 + threadIdx.x;
  if (idx >= N_GRAPHS * N_OUT * 2) return;
  int which = idx >> 9;
  int rem = idx & 511;
  int row = rem >> 3, col = rem & 7;
  const float* w = which ? w2 : w1;
  float s = which ? b2[col] : b1[col];
  for (int k = 0; k < HIDDEN; ++k) s = fmaf(g[row * HIDDEN + k], w[k * N_OUT + col], s);
  out[idx] = s;
}

extern "C" void kernel_launch(void* const* d_in, const int* in_sizes, int n_in,
                              void* d_out, int out_size, void* d_ws, size_t ws_size,
                              hipStream_t stream) {
  const float* x     = (const float*)d_in[0];
  const int*   ei    = (const int*)d_in[1];
  const float* eattr = (const float*)d_in[2];
  const int*   batch = (const int*)d_in[3];
  const float* Wl1   = (const float*)d_in[4];
  const float* Wr1   = (const float*)d_in[5];
  const float* We1   = (const float*)d_in[6];
  const float* bl1   = (const float*)d_in[7];
  const float* br1   = (const float*)d_in[8];
  const float* att1  = (const float*)d_in[9];
  const float* b1    = (const float*)d_in[10];
  const float* Wls   = (const float*)d_in[11];
  const float* Wrs   = (const float*)d_in[12];
  const float* Wes   = (const float*)d_in[13];
  const float* bls   = (const float*)d_in[14];
  const float* brs   = (const float*)d_in[15];
  const float* atts  = (const float*)d_in[16];
  const float* bs    = (const float*)d_in[17];
  const float* bng   = (const float*)d_in[18];
  const float* bnb   = (const float*)d_in[19];
  const float* bnm   = (const float*)d_in[20];
  const float* bnv   = (const float*)d_in[21];
  const float* l1w   = (const float*)d_in[22];
  const float* l1b   = (const float*)d_in[23];
  const float* l2w   = (const float*)d_in[24];
  const float* l2b   = (const float*)d_in[25];
  float* out = (float*)d_out;

  char* ws = (char*)d_ws;
  auto alloc = [&](size_t bytes) {
    char* p = ws;
    ws += (bytes + 255) & ~(size_t)255;
    return p;
  };
  int*   counts   = (int*)alloc((size_t)N_NODES * 4);
  int*   offs     = (int*)alloc((size_t)(N_NODES + 1) * 4);
  int*   cursor   = (int*)alloc((size_t)N_NODES * 4);
  int*   csr_src  = (int*)alloc((size_t)N_EDGES * 4);
  float* csr_attr = (float*)alloc((size_t)N_EDGES * 16 * 4);
  float* xlr      = (float*)alloc((size_t)N_NODES * 512 * 4);
  float* hA       = (float*)alloc((size_t)N_NODES * 256 * 4);
  float* hB       = (float*)alloc((size_t)N_NODES * 256 * 4);
  float* g        = (float*)alloc((size_t)N_GRAPHS * 256 * 4);

  hipMemsetAsync(counts, 0, (size_t)N_NODES * 4, stream);
  hist_kernel<<<(N_EDGES + 255) / 256, 256, 0, stream>>>(ei + N_EDGES, counts, N_EDGES);
  scan_kernel<<<1, 256, 0, stream>>>(counts, offs, cursor, N_NODES);
  scatter_kernel<<<(N_EDGES + 255) / 256, 256, 0, stream>>>(ei, eattr, cursor, csr_src,
                                                            csr_attr, N_EDGES);

  dim3 gemm_grid((N_NODES + 63) / 64, 8);
  const float* hin = x;
  for (int layer = 0; layer < 5; ++layer) {
    int K = (layer == 0) ? NODE_DIM : HIDDEN;
    const float* Wl = (layer == 0) ? Wl1 : Wls + (size_t)(layer - 1) * HIDDEN * HIDDEN;
    const float* Wr = (layer == 0) ? Wr1 : Wrs + (size_t)(layer - 1) * HIDDEN * HIDDEN;
    const float* We = (layer == 0) ? We1 : Wes + (size_t)(layer - 1) * EDGE_DIM * HIDDEN;
    const float* bl = (layer == 0) ? bl1 : bls + (layer - 1) * HIDDEN;
    const float* br = (layer == 0) ? br1 : brs + (layer - 1) * HIDDEN;
    const float* at = (layer == 0) ? att1 : atts + (layer - 1) * HIDDEN;
    const float* bc = (layer == 0) ? b1 : bs + (layer - 1) * HIDDEN;
    float* hout = (layer & 1) ? hB : hA;
    gemm_node<<<gemm_grid, 256, 0, stream>>>(hin, N_NODES, K, Wl, Wr, bl, br, xlr);
    edge_gat<<<N_NODES / 4, 256, 0, stream>>>(xlr, offs, csr_src, csr_attr, We, at, bc,
                                              bng + layer * HIDDEN, bnb + layer * HIDDEN,
                                              bnm + layer * HIDDEN, bnv + layer * HIDDEN,
                                              hout, (layer == 4) ? 1 : 0);
    hin = hout;
  }
  pool_kernel<<<N_GRAPHS, 256, 0, stream>>>(hin, batch, g);
  head_kernel<<<4, 256, 0, stream>>>(g, l1w, l1b, l2w, l2b, out);
}